// Round 4
// baseline (608.931 us; speedup 1.0000x reference)
//
#include <hip/hip_runtime.h>
#include <math.h>

#define B_ 2
#define N_ 16384
#define D_ 512
#define C_ 4
#define K_ 8
#define ROWS (B_*N_)   // 32768
#define EPS_ 1e-12f

typedef unsigned short u16;
typedef unsigned int u32;
using short8  = __attribute__((ext_vector_type(8))) short;
using float4v = __attribute__((ext_vector_type(4))) float;

__device__ __forceinline__ u16 f2bf(float f) {
    union { float f; u32 u; } v; v.f = f;
    u32 r = v.u + 0x7fffu + ((v.u >> 16) & 1u);
    return (u16)(r >> 16);
}
__device__ __forceinline__ u32 pack2(float a, float b) {
    return (u32)f2bf(a) | ((u32)f2bf(b) << 16);
}
__device__ __forceinline__ u32 packtrunc2(float a, float b) {
    union { float f; u32 u; } va, vb; va.f = a; vb.f = b;
    return (va.u >> 16) | (vb.u & 0xffff0000u);
}
__device__ __forceinline__ float bf2f(u16 h) {
    union { u32 u; float f; } v; v.u = ((u32)h) << 16;
    return v.f;
}
__device__ __forceinline__ void load_lds16(const u16* g, u16* l) {
    __builtin_amdgcn_global_load_lds(
        (const __attribute__((address_space(1))) u32*)g,
        (__attribute__((address_space(3))) u32*)l, 16, 0, 0);
}

// ---------------- P0: weight prep ----------------
// WpT[n][k] = Wp[k][n]  (bf16)
// WvuT fine-interleave: col n -> tile=n>>4, pair=tile>>1, half=tile&1, h=pair*16+(n&15)
//   WvuT[n][k] = half ? Wu[k][h] : Wv[k][h];  bvu[n] likewise.
// descF: MFMA B-fragment order.
__global__ __launch_bounds__(256) void prep_weights_kernel(
    const float* __restrict__ Wp, const float* __restrict__ Wv, const float* __restrict__ Wu,
    const float* __restrict__ bv, const float* __restrict__ bu, const float* __restrict__ desc,
    u16* __restrict__ WpT, u16* __restrict__ WvuT, float* __restrict__ bvu,
    u16* __restrict__ descF)
{
    int idx = blockIdx.x * 256 + threadIdx.x;   // 0 .. 262143
    int n = idx >> 9, k = idx & 511;
    WpT[idx] = f2bf(Wp[k * 512 + n]);
    int tile = n >> 4, pair = tile >> 1, half = tile & 1, h = pair * 16 + (n & 15);
    WvuT[idx] = f2bf(half ? Wu[k * 256 + h] : Wv[k * 256 + h]);
    if (idx < 512) {
        int tl = idx >> 4, pr = tl >> 1, hf = tl & 1, hh = pr * 16 + (idx & 15);
        bvu[idx] = hf ? bu[hh] : bv[hh];
    }
    if (idx < 16384) {
        int j = idx & 7, l = (idx >> 3) & 63, g = (idx >> 9) & 1, kt = idx >> 10;
        descF[idx] = f2bf(desc[(size_t)(g * 16 + (l & 15)) * 512 + kt * 32 + (l >> 4) * 8 + j]);
    }
}

// ---------------- K1: fused l2norm(x) @ Wp + b  -> xpraw (bf16) ----------------
// LDS-free GEMM. Block = 64 rows x 256 cols (4 waves x 64 cols); grid (512 Mtiles, 2 Nhalves).
// A loaded fp32 direct from x, truncation-cast to bf16 frags; row-norm of x via Gram-MFMA
// diag (wave 0), broadcast through tiny LDS; epilogue: acc*invnx + bias.
__global__ __launch_bounds__(256) void proj_kernel(
    const float* __restrict__ X, const u16* __restrict__ Bt,
    const float* __restrict__ bias, u16* __restrict__ C)
{
    __shared__ float sN[64];
    int t = threadIdx.x, wave = t >> 6, lane = t & 63;
    int lr = lane & 15, lq = lane >> 4;
    int M0 = blockIdx.x * 64;
    int g = blockIdx.y * 4 + wave;       // 0..7
    int n0 = g * 64;

    float4v acc[4][4];
    float4v accG[4];
#pragma unroll
    for (int i = 0; i < 4; ++i) {
#pragma unroll
        for (int r = 0; r < 4; ++r) accG[i][r] = 0.f;
#pragma unroll
        for (int j = 0; j < 4; ++j)
#pragma unroll
            for (int r = 0; r < 4; ++r) acc[i][j][r] = 0.f;
    }

    const float* aBase = X + (size_t)(M0 + lr) * 512 + lq * 8;
    const u16*  bBase  = Bt + (size_t)(n0 + lr) * 512 + lq * 8;

#pragma unroll 2
    for (int kt = 0; kt < 16; ++kt) {
        short8 af[4], bfr[4];
#pragma unroll
        for (int i = 0; i < 4; ++i) {
            const float* p = aBase + (size_t)i * 16 * 512 + kt * 32;
            float4 f0 = *(const float4*)p;
            float4 f1 = *(const float4*)(p + 4);
            union { u32 u[4]; short8 s; } cv;
            cv.u[0] = packtrunc2(f0.x, f0.y);
            cv.u[1] = packtrunc2(f0.z, f0.w);
            cv.u[2] = packtrunc2(f1.x, f1.y);
            cv.u[3] = packtrunc2(f1.z, f1.w);
            af[i] = cv.s;
        }
#pragma unroll
        for (int j = 0; j < 4; ++j)
            bfr[j] = *(const short8*)(bBase + (size_t)j * 16 * 512 + kt * 32);
#pragma unroll
        for (int i = 0; i < 4; ++i)
#pragma unroll
            for (int j = 0; j < 4; ++j)
                acc[i][j] = __builtin_amdgcn_mfma_f32_16x16x32_bf16(bfr[j], af[i], acc[i][j], 0, 0, 0);
        if (wave == 0) {
#pragma unroll
            for (int i = 0; i < 4; ++i)
                accG[i] = __builtin_amdgcn_mfma_f32_16x16x32_bf16(af[i], af[i], accG[i], 0, 0, 0);
        }
    }
    if (wave == 0) {
        // G layout: lane holds G[row=lq*4+r][col=lr]; diag where lr==lq*4+r
#pragma unroll
        for (int i = 0; i < 4; ++i)
#pragma unroll
            for (int r = 0; r < 4; ++r)
                if (lr == lq * 4 + r) sN[i * 16 + lq * 4 + r] = accG[i][r];
    }
    __syncthreads();
#pragma unroll
    for (int i = 0; i < 4; ++i) {
        int m = M0 + i * 16 + lr;
        float iv = 1.0f / fmaxf(sqrtf(sN[i * 16 + lr]), EPS_);
        u16* crow = C + (size_t)m * 512;
#pragma unroll
        for (int j = 0; j < 4; ++j) {
            int nb = n0 + j * 16 + lq * 4;
            float4 b4 = *(const float4*)&bias[nb];
            uint2 o;
            o.x = pack2(acc[i][j][0] * iv + b4.x, acc[i][j][1] * iv + b4.y);
            o.y = pack2(acc[i][j][2] * iv + b4.z, acc[i][j][3] * iv + b4.w);
            *(uint2*)&crow[nb] = o;
        }
    }
}

// ---------------- K2: MFMA class scores + row inv-norm (Gram-diag trick) ----------------
__global__ __launch_bounds__(256) void classscore_kernel(
    const u16* __restrict__ xpraw, const u16* __restrict__ descF,
    float* __restrict__ invn, float* __restrict__ cls_out)
{
    __shared__ u16 descL[16384];   // 32KB: 16 k-tiles x 2 groups, fragment order
    __shared__ float sInv[4][16];
    int t = threadIdx.x, wave = t >> 6, lane = t & 63;
    int lr = lane & 15, lq = lane >> 4;
#pragma unroll
    for (int s = 0; s < 8; ++s) {
        int u = wave * 8 + s;
        load_lds16(descF + u * 512 + lane * 8, descL + u * 512);
    }
    int base0 = blockIdx.x * 64 + wave * 16;
    short8 af[16];
#pragma unroll
    for (int kt = 0; kt < 16; ++kt)
        af[kt] = *(const short8*)(xpraw + (size_t)(base0 + lr) * 512 + kt * 32 + lq * 8);
    __syncthreads();

    float4v accS0 = {0.f, 0.f, 0.f, 0.f};
    float4v accS1 = {0.f, 0.f, 0.f, 0.f};
    float4v accG  = {0.f, 0.f, 0.f, 0.f};
#pragma unroll
    for (int kt = 0; kt < 16; ++kt) {
        short8 d0 = *(const short8*)&descL[(kt * 2 + 0) * 512 + lane * 8];
        short8 d1 = *(const short8*)&descL[(kt * 2 + 1) * 512 + lane * 8];
        accS0 = __builtin_amdgcn_mfma_f32_16x16x32_bf16(af[kt], d0, accS0, 0, 0, 0);
        accS1 = __builtin_amdgcn_mfma_f32_16x16x32_bf16(af[kt], d1, accS1, 0, 0, 0);
        accG  = __builtin_amdgcn_mfma_f32_16x16x32_bf16(af[kt], af[kt], accG, 0, 0, 0);
    }
#pragma unroll
    for (int r = 0; r < 4; ++r) {
        if (lr == lq * 4 + r) {
            float iv = 1.0f / fmaxf(sqrtf(accG[r]), EPS_);
            sInv[wave][lq * 4 + r] = iv;
            invn[base0 + lq * 4 + r] = iv;
        }
    }
    __syncthreads();
    const float scale = 0.04419417382415922f;   // 512^-0.5
#pragma unroll
    for (int r = 0; r < 4; ++r) {
        int row = base0 + lq * 4 + r;
        float iv = sInv[wave][lq * 4 + r];
        float sv0 = accS0[r] * iv, sv1 = accS1[r] * iv;
#pragma unroll
        for (int g = 0; g < 2; ++g) {
            float s = g ? sv1 : sv0;
            float ts = s * scale;
            float mx = ts;
            mx = fmaxf(mx, __shfl_xor(mx, 1, 64));
            mx = fmaxf(mx, __shfl_xor(mx, 2, 64));
            mx = fmaxf(mx, __shfl_xor(mx, 4, 64));
            float e = expf(ts - mx);
            float num = e * s, den = e;
            num += __shfl_xor(num, 1, 64); den += __shfl_xor(den, 1, 64);
            num += __shfl_xor(num, 2, 64); den += __shfl_xor(den, 2, 64);
            num += __shfl_xor(num, 4, 64); den += __shfl_xor(den, 4, 64);
            if ((lr & 7) == 0) {
                int c = g * 2 + ((lr >> 3) & 1);
                cls_out[(size_t)row * 4 + c] = num / den;
            }
        }
    }
}

// ---------------- K3: LDS-free GEMM2 + fully in-register gated-attention ----------------
// WvuT fine-interleaved: wave's 4 n-tiles = (v,u,v,u) for h in [32g, 32g+32).
__global__ __launch_bounds__(256) void gate_kernel(
    const u16* __restrict__ A, const u16* __restrict__ Bt,
    const float* __restrict__ bvu, const float* __restrict__ invn,
    const float* __restrict__ w_attn, float* __restrict__ Araw)
{
    int t = threadIdx.x, wave = t >> 6, lane = t & 63;
    int lr = lane & 15, lq = lane >> 4;
    int M0 = blockIdx.x * 64;
    int g = blockIdx.y * 4 + wave;       // 0..7
    int n0 = g * 64;

    float4v acc[4][4];
#pragma unroll
    for (int i = 0; i < 4; ++i)
#pragma unroll
        for (int j = 0; j < 4; ++j)
#pragma unroll
            for (int r = 0; r < 4; ++r) acc[i][j][r] = 0.f;

    const u16* aBase = A  + (size_t)(M0 + lr) * 512 + lq * 8;
    const u16* bBase = Bt + (size_t)(n0 + lr) * 512 + lq * 8;

#pragma unroll 2
    for (int kt = 0; kt < 16; ++kt) {
        short8 af[4], bfr[4];
#pragma unroll
        for (int i = 0; i < 4; ++i)
            af[i] = *(const short8*)(aBase + (size_t)i * 16 * 512 + kt * 32);
#pragma unroll
        for (int j = 0; j < 4; ++j)
            bfr[j] = *(const short8*)(bBase + (size_t)j * 16 * 512 + kt * 32);
#pragma unroll
        for (int i = 0; i < 4; ++i)
#pragma unroll
            for (int j = 0; j < 4; ++j)
                acc[i][j] = __builtin_amdgcn_mfma_f32_16x16x32_bf16(bfr[j], af[i], acc[i][j], 0, 0, 0);
    }

#pragma unroll
    for (int i = 0; i < 4; ++i) {
        int m = M0 + i * 16 + lr;
        float iv = invn[m];
        float part = 0.f;
#pragma unroll
        for (int p = 0; p < 2; ++p) {
            int nb = n0 + (2 * p) * 16 + lq * 4;
            float4 bv4 = *(const float4*)&bvu[nb];
            float4 bu4 = *(const float4*)&bvu[nb + 16];
            int h0 = 32 * g + p * 16 + lq * 4;
            float4 w4 = *(const float4*)&w_attn[h0];
#pragma unroll
            for (int r = 0; r < 4; ++r) {
                float v = acc[i][2 * p][r] * iv + (&bv4.x)[r];
                float u = acc[i][2 * p + 1][r] * iv + (&bu4.x)[r];
                part += tanhf(v) * (&w4.x)[r] * (1.0f / (1.0f + expf(-u)));
            }
        }
        part += __shfl_xor(part, 16, 64);
        part += __shfl_xor(part, 32, 64);
        if (lq == 0) atomicAdd(&Araw[m], part);
    }
}

// ---------------- K5: softmax over N per batch, fused *invn ----------------
__global__ __launch_bounds__(256) void softmaxN_kernel(float* __restrict__ A,
                                                       const float* __restrict__ invn)
{
    __shared__ float red[256];
    int t = threadIdx.x;
    float* Ab = A + (size_t)blockIdx.x * N_;
    const float* ivb = invn + (size_t)blockIdx.x * N_;
    float m = -1e30f;
    for (int i = t; i < N_; i += 256) m = fmaxf(m, Ab[i]);
    red[t] = m; __syncthreads();
    for (int s = 128; s; s >>= 1) { if (t < s) red[t] = fmaxf(red[t], red[t + s]); __syncthreads(); }
    m = red[0]; __syncthreads();
    float sum = 0.f;
    for (int i = t; i < N_; i += 256) { float e = expf(Ab[i] - m); Ab[i] = e; sum += e; }
    red[t] = sum; __syncthreads();
    for (int s = 128; s; s >>= 1) { if (t < s) red[t] += red[t + s]; __syncthreads(); }
    float inv = 1.0f / red[0];
    for (int i = t; i < N_; i += 256) Ab[i] = Ab[i] * inv * ivb[i];
}

// ---------------- K6: weighted pooling  slide[b] += sum Asc[n]*xpraw[n] ----------------
__global__ __launch_bounds__(256) void pool_kernel(
    const float* __restrict__ Asc, const u16* __restrict__ xpraw, float* __restrict__ slide)
{
    int b = blockIdx.y;
    int t = threadIdx.x;
    size_t base = (size_t)b * N_ + (size_t)blockIdx.x * 64;
    float a0 = 0.f, a1 = 0.f;
#pragma unroll 4
    for (int r = 0; r < 64; ++r) {
        size_t row = base + r;
        float a = Asc[row];
        u32 pk = *(const u32*)&xpraw[row * D_ + 2 * t];
        a0 += a * bf2f((u16)pk);
        a1 += a * bf2f((u16)(pk >> 16));
    }
    atomicAdd(&slide[b * D_ + 2 * t], a0);
    atomicAdd(&slide[b * D_ + 2 * t + 1], a1);
}

// ---------------- K7: finalize ----------------
__global__ __launch_bounds__(512) void finalize_kernel(
    const float* __restrict__ slide_s, const float* __restrict__ slide_l,
    const float* __restrict__ desc, float* __restrict__ out)
{
    __shared__ float txt[4][512];
    __shared__ float ssn[2][512];
    __shared__ float sln[2][512];
    __shared__ float red[512];
    __shared__ float lg[8];
    int t = threadIdx.x;

    auto reduceSum = [&](float v) -> float {
        red[t] = v; __syncthreads();
        for (int s = 256; s; s >>= 1) { if (t < s) red[t] += red[t + s]; __syncthreads(); }
        float r = red[0]; __syncthreads();
        return r;
    };

    for (int c = 0; c < 4; ++c) {
        float m = -1e30f;
        for (int k = 0; k < 8; ++k) m = fmaxf(m, desc[((size_t)c * 8 + k) * 512 + t]);
        float ss = reduceSum(m * m);
        txt[c][t] = m / fmaxf(sqrtf(ss), EPS_);
    }
    for (int b = 0; b < 2; ++b) {
        float v = slide_s[b * 512 + t];
        float ss = reduceSum(v * v);
        ssn[b][t] = v / fmaxf(sqrtf(ss), EPS_);
        v = slide_l[b * 512 + t];
        ss = reduceSum(v * v);
        sln[b][t] = v / fmaxf(sqrtf(ss), EPS_);
    }
    __syncthreads();
    for (int b = 0; b < 2; ++b)
        for (int c = 0; c < 4; ++c) {
            float v = ssn[b][t] * txt[c][t] + sln[b][t] * txt[c][t];
            float s = reduceSum(v);
            if (t == 0) lg[b * 4 + c] = s;
        }
    __syncthreads();
    if (t < 2) {
        int b = t;
        float m = -1e30f;
        for (int c = 0; c < 4; ++c) m = fmaxf(m, lg[b * 4 + c]);
        float e[4]; float den = 0.f;
        for (int c = 0; c < 4; ++c) { e[c] = expf(lg[b * 4 + c] - m); den += e[c]; }
        int am = 0; float bm = -1.f;
        for (int c = 0; c < 4; ++c) {
            float pcl = e[c] / den;
            out[b * 4 + c] = pcl;
            if (pcl > bm) { bm = pcl; am = c; }
        }
        out[8 + b] = (float)am;
    }
}

extern "C" void kernel_launch(void* const* d_in, const int* in_sizes, int n_in,
                              void* d_out, int out_size, void* d_ws, size_t ws_size,
                              hipStream_t stream) {
    const float* x_s    = (const float*)d_in[0];
    const float* x_l    = (const float*)d_in[2];
    const float* W_proj = (const float*)d_in[4];
    const float* b_proj = (const float*)d_in[5];
    const float* desc   = (const float*)d_in[6];
    const float* Wv     = (const float*)d_in[7];
    const float* bv     = (const float*)d_in[8];
    const float* Wu     = (const float*)d_in[9];
    const float* bu     = (const float*)d_in[10];
    const float* w_attn = (const float*)d_in[11];
    float* out = (float*)d_out;

    // workspace layout (bytes):
    //  0        : xpraw bf16 [32768x512]  (33554432)
    //  33554432 : WpT   bf16 [512x512]    (524288)
    //  34078720 : WvuT  bf16 [512x512]    (524288, fine-interleaved)
    //  34603008 : descF bf16 fragment     (32768)
    //  34635776 : bvu   f32 [512]         (2048, fine-interleaved)
    //  34637824 : invn  f32 [32768]       (131072)
    //  34768896 : slide_s f32 [2x512]     (4096)
    //  34772992 : slide_l f32 [2x512]     (4096)
    //  34777088 : Araw0 f32 [32768]       (131072)
    //  34908160 : Araw1 f32 [32768]       (131072)
    char* w = (char*)d_ws;
    u16* xpraw   = (u16*)w;
    u16* WpT     = (u16*)(w + 33554432);
    u16* WvuT    = (u16*)(w + 34078720);
    u16* descF   = (u16*)(w + 34603008);
    float* bvu   = (float*)(w + 34635776);
    float* invn  = (float*)(w + 34637824);
    float* slide_s = (float*)(w + 34768896);
    float* slide_l = (float*)(w + 34772992);
    float* Araw0 = (float*)(w + 34777088);

    // zero slides + Araw0 + Araw1 (contiguous 270336 B)
    hipMemsetAsync(slide_s, 0, 270336, stream);
    prep_weights_kernel<<<1024, 256, 0, stream>>>(W_proj, Wv, Wu, bv, bu, desc,
                                                  WpT, WvuT, bvu, descF);

    float* cls_s = out + 10;
    float* cls_l = out + 10 + (size_t)ROWS * C_;

    for (int s = 0; s < 2; ++s) {
        const float* x = s ? x_l : x_s;
        float* cls     = s ? cls_l : cls_s;
        float* slide   = s ? slide_l : slide_s;
        float* Araw    = Araw0 + (size_t)s * ROWS;

        proj_kernel<<<dim3(ROWS / 64, 2), 256, 0, stream>>>(x, WpT, b_proj, xpraw);
        classscore_kernel<<<ROWS / 64, 256, 0, stream>>>(xpraw, descF, invn, cls);
        gate_kernel<<<dim3(ROWS / 64, 2), 256, 0, stream>>>(xpraw, WvuT, bvu, invn, w_attn, Araw);
        softmaxN_kernel<<<2, 256, 0, stream>>>(Araw, invn);
        pool_kernel<<<dim3(N_ / 64, 2), 256, 0, stream>>>(Araw, xpraw, slide);
    }
    finalize_kernel<<<1, 512, 0, stream>>>(slide_s, slide_l, desc, out);
}

// Round 5
// 533.690 us; speedup vs baseline: 1.1410x; 1.1410x over previous
//
#include <hip/hip_runtime.h>
#include <math.h>

#define B_ 2
#define N_ 16384
#define D_ 512
#define C_ 4
#define K_ 8
#define ROWS (B_*N_)   // 32768
#define EPS_ 1e-12f

typedef unsigned short u16;
typedef unsigned int u32;
using short8  = __attribute__((ext_vector_type(8))) short;
using float4v = __attribute__((ext_vector_type(4))) float;

__device__ __forceinline__ u16 f2bf(float f) {
    union { float f; u32 u; } v; v.f = f;
    u32 r = v.u + 0x7fffu + ((v.u >> 16) & 1u);
    return (u16)(r >> 16);
}
__device__ __forceinline__ u32 pack2(float a, float b) {
    return (u32)f2bf(a) | ((u32)f2bf(b) << 16);
}
__device__ __forceinline__ float bf2f(u16 h) {
    union { u32 u; float f; } v; v.u = ((u32)h) << 16;
    return v.f;
}
__device__ __forceinline__ void load_lds16(const u16* g, u16* l) {
    __builtin_amdgcn_global_load_lds(
        (const __attribute__((address_space(1))) u32*)g,
        (__attribute__((address_space(3))) u32*)l, 16, 0, 0);
}
// Stage 8 rows x 64 k (bf16) of a row-major tile (row stride 512 u16) into LDS,
// fully coalesced (each instr = 8 rows x 128B contiguous), with XOR swizzle so
// fragment ds_read_b128 is conflict-free. LDS layout: addr(r,c)=r*64 + (c^(r&7))*8 (u16).
__device__ __forceinline__ void stage_rows8(const u16* gtile, u16* ldsTile, int g, int lane) {
    int rg = lane >> 3;                 // row in group 0..7
    int c  = (lane & 7) ^ rg;           // source chunk for stored slot (lane&7)
    load_lds16(gtile + (size_t)(g * 8 + rg) * 512 + c * 8, ldsTile + g * 512);
}
#define AFRAG(lds, R, c) (*(const short8*)&(lds)[(R) * 64 + (((c) ^ ((R) & 7)) * 8)])

// ---------------- P0: weight prep (round-4 scheme) ----------------
__global__ __launch_bounds__(256) void prep_weights_kernel(
    const float* __restrict__ Wp, const float* __restrict__ Wv, const float* __restrict__ Wu,
    const float* __restrict__ bv, const float* __restrict__ bu, const float* __restrict__ desc,
    u16* __restrict__ WpT, u16* __restrict__ WvuT, float* __restrict__ bvu,
    u16* __restrict__ descF)
{
    int idx = blockIdx.x * 256 + threadIdx.x;   // 0 .. 262143
    int n = idx >> 9, k = idx & 511;
    WpT[idx] = f2bf(Wp[k * 512 + n]);
    int tile = n >> 4, pair = tile >> 1, half = tile & 1, h = pair * 16 + (n & 15);
    WvuT[idx] = f2bf(half ? Wu[k * 256 + h] : Wv[k * 256 + h]);
    if (idx < 512) {
        int tl = idx >> 4, pr = tl >> 1, hf = tl & 1, hh = pr * 16 + (idx & 15);
        bvu[idx] = hf ? bu[hh] : bv[hh];
    }
    if (idx < 16384) {
        int j = idx & 7, l = (idx >> 3) & 63, g = (idx >> 9) & 1, kt = idx >> 10;
        descF[idx] = f2bf(desc[(size_t)(g * 16 + (l & 15)) * 512 + kt * 32 + (l >> 4) * 8 + j]);
    }
}

// ---------------- K0: per-row L2-normalize x and cast to bf16 ----------------
__global__ __launch_bounds__(256) void rownorm_cast_kernel(
    const float* __restrict__ x, u16* __restrict__ xn)
{
    int wave = threadIdx.x >> 6, lane = threadIdx.x & 63;
    size_t row = (size_t)blockIdx.x * 4 + wave;
    const float* xr = x + row * D_;
    float4 a = *(const float4*)&xr[lane * 8];
    float4 b = *(const float4*)&xr[lane * 8 + 4];
    float s = a.x*a.x + a.y*a.y + a.z*a.z + a.w*a.w
            + b.x*b.x + b.y*b.y + b.z*b.z + b.w*b.w;
#pragma unroll
    for (int off = 32; off; off >>= 1) s += __shfl_xor(s, off, 64);
    float inv = 1.0f / fmaxf(sqrtf(s), EPS_);
    uint4 o;
    o.x = pack2(a.x * inv, a.y * inv);
    o.y = pack2(a.z * inv, a.w * inv);
    o.z = pack2(b.x * inv, b.y * inv);
    o.w = pack2(b.z * inv, b.w * inv);
    *(uint4*)&xn[row * D_ + lane * 8] = o;
}

// ---------------- K1: GEMM xpraw = xn @ WpT^T + bias.  Block 128x256, BK=64.
// A staged (coalesced+swizzled), B direct global->VGPR (L2-hot, 512KB).
// Waves 2x2; wave tile 64x128 (acc[4][8]); swapped mfma => C[m=..+lr][n=..+lq*4+r].
__global__ __launch_bounds__(256, 2) void gemm_bias_kernel(
    const u16* __restrict__ A, const u16* __restrict__ Bt,
    const float* __restrict__ bias, u16* __restrict__ C)
{
    __shared__ u16 ldsA[128 * 64];
    int t = threadIdx.x, wave = t >> 6, lane = t & 63;
    int lr = lane & 15, lq = lane >> 4;
    int wm = wave >> 1, wn = wave & 1;
    int M0 = blockIdx.x * 128, N0 = blockIdx.y * 256;

    float4v acc[4][8];
#pragma unroll
    for (int i = 0; i < 4; ++i)
#pragma unroll
        for (int j = 0; j < 8; ++j)
#pragma unroll
            for (int r = 0; r < 4; ++r) acc[i][j][r] = 0.f;

    for (int k0 = 0; k0 < 512; k0 += 64) {
        const u16* Ab = A + (size_t)M0 * 512 + k0;
#pragma unroll
        for (int s = 0; s < 4; ++s) stage_rows8(Ab, ldsA, wave * 4 + s, lane);
        __syncthreads();
#pragma unroll
        for (int kt = 0; kt < 2; ++kt) {
            short8 af[4], bfr[8];
#pragma unroll
            for (int i = 0; i < 4; ++i)
                af[i] = AFRAG(ldsA, wm * 64 + i * 16 + lr, kt * 4 + lq);
            const u16* Bb = Bt + (size_t)(N0 + wn * 128 + lr) * 512 + k0 + kt * 32 + lq * 8;
#pragma unroll
            for (int j = 0; j < 8; ++j)
                bfr[j] = *(const short8*)(Bb + (size_t)j * 16 * 512);
#pragma unroll
            for (int i = 0; i < 4; ++i)
#pragma unroll
                for (int j = 0; j < 8; ++j)
                    acc[i][j] = __builtin_amdgcn_mfma_f32_16x16x32_bf16(bfr[j], af[i], acc[i][j], 0, 0, 0);
        }
        __syncthreads();
    }

    float4 b4[8];
#pragma unroll
    for (int j = 0; j < 8; ++j)
        b4[j] = *(const float4*)&bias[N0 + wn * 128 + j * 16 + lq * 4];
#pragma unroll
    for (int i = 0; i < 4; ++i) {
        int m = M0 + wm * 64 + i * 16 + lr;
        u16* crow = C + (size_t)m * 512;
#pragma unroll
        for (int j = 0; j < 8; ++j) {
            int nb = N0 + wn * 128 + j * 16 + lq * 4;
            uint2 o;
            o.x = pack2(acc[i][j][0] + b4[j].x, acc[i][j][1] + b4[j].y);
            o.y = pack2(acc[i][j][2] + b4[j].z, acc[i][j][3] + b4[j].w);
            *(uint2*)&crow[nb] = o;
        }
    }
}

// ---------------- K2: class scores + row inv-norm. Block 128 rows, staged A. ------
__global__ __launch_bounds__(256) void classscore_kernel(
    const u16* __restrict__ xpraw, const u16* __restrict__ descF,
    float* __restrict__ invn, float* __restrict__ cls_out)
{
    __shared__ u16 ldsA[128 * 64];
    __shared__ u16 descL[16384];
    __shared__ float sInv[4][2][16];
    int t = threadIdx.x, wave = t >> 6, lane = t & 63;
    int lr = lane & 15, lq = lane >> 4;
    int rows0 = blockIdx.x * 128;

#pragma unroll
    for (int s = 0; s < 8; ++s) {
        int u = wave * 8 + s;
        load_lds16(descF + u * 512 + lane * 8, descL + u * 512);
    }

    float4v accS[2][2], accG[2];
#pragma unroll
    for (int h = 0; h < 2; ++h) {
#pragma unroll
        for (int r = 0; r < 4; ++r) { accS[h][0][r] = 0.f; accS[h][1][r] = 0.f; accG[h][r] = 0.f; }
    }

    for (int k0 = 0; k0 < 512; k0 += 64) {
        const u16* Ab = xpraw + (size_t)rows0 * 512 + k0;
#pragma unroll
        for (int s = 0; s < 4; ++s) stage_rows8(Ab, ldsA, wave * 4 + s, lane);
        __syncthreads();
#pragma unroll
        for (int kt = 0; kt < 2; ++kt) {
            int ktg = (k0 >> 5) + kt;
            short8 d0 = *(const short8*)&descL[(ktg * 2 + 0) * 512 + lane * 8];
            short8 d1 = *(const short8*)&descL[(ktg * 2 + 1) * 512 + lane * 8];
#pragma unroll
            for (int h = 0; h < 2; ++h) {
                short8 af = AFRAG(ldsA, wave * 32 + h * 16 + lr, kt * 4 + lq);
                accS[h][0] = __builtin_amdgcn_mfma_f32_16x16x32_bf16(af, d0, accS[h][0], 0, 0, 0);
                accS[h][1] = __builtin_amdgcn_mfma_f32_16x16x32_bf16(af, d1, accS[h][1], 0, 0, 0);
                accG[h]    = __builtin_amdgcn_mfma_f32_16x16x32_bf16(af, af, accG[h], 0, 0, 0);
            }
        }
        __syncthreads();
    }

#pragma unroll
    for (int h = 0; h < 2; ++h) {
        int base0 = rows0 + wave * 32 + h * 16;
#pragma unroll
        for (int r = 0; r < 4; ++r) {
            if (lr == lq * 4 + r) {
                float iv = 1.0f / fmaxf(sqrtf(accG[h][r]), EPS_);
                sInv[wave][h][lq * 4 + r] = iv;
                invn[base0 + lq * 4 + r] = iv;
            }
        }
    }
    __syncthreads();
    const float scale = 0.04419417382415922f;   // 512^-0.5
#pragma unroll
    for (int h = 0; h < 2; ++h) {
        int base0 = rows0 + wave * 32 + h * 16;
#pragma unroll
        for (int r = 0; r < 4; ++r) {
            int row = base0 + lq * 4 + r;
            float iv = sInv[wave][h][lq * 4 + r];
            float sv0 = accS[h][0][r] * iv, sv1 = accS[h][1][r] * iv;
#pragma unroll
            for (int g = 0; g < 2; ++g) {
                float s = g ? sv1 : sv0;
                float ts = s * scale;
                float mx = ts;
                mx = fmaxf(mx, __shfl_xor(mx, 1, 64));
                mx = fmaxf(mx, __shfl_xor(mx, 2, 64));
                mx = fmaxf(mx, __shfl_xor(mx, 4, 64));
                float e = expf(ts - mx);
                float num = e * s, den = e;
                num += __shfl_xor(num, 1, 64); den += __shfl_xor(den, 1, 64);
                num += __shfl_xor(num, 2, 64); den += __shfl_xor(den, 2, 64);
                num += __shfl_xor(num, 4, 64); den += __shfl_xor(den, 4, 64);
                if ((lr & 7) == 0) {
                    int c = g * 2 + ((lr >> 3) & 1);
                    cls_out[(size_t)row * 4 + c] = num / den;
                }
            }
        }
    }
}

// ---------------- K3: GEMM2 + in-register gated attention, partials to 4 slabs ----
__global__ __launch_bounds__(256, 2) void gate_kernel(
    const u16* __restrict__ A, const u16* __restrict__ Bt,
    const float* __restrict__ bvu, const float* __restrict__ invn,
    const float* __restrict__ w_attn, float* __restrict__ Araw4)
{
    __shared__ u16 ldsA[128 * 64];
    int t = threadIdx.x, wave = t >> 6, lane = t & 63;
    int lr = lane & 15, lq = lane >> 4;
    int wm = wave >> 1, wn = wave & 1;
    int M0 = blockIdx.x * 128, N0 = blockIdx.y * 256;

    float4v acc[4][8];
#pragma unroll
    for (int i = 0; i < 4; ++i)
#pragma unroll
        for (int j = 0; j < 8; ++j)
#pragma unroll
            for (int r = 0; r < 4; ++r) acc[i][j][r] = 0.f;

    for (int k0 = 0; k0 < 512; k0 += 64) {
        const u16* Ab = A + (size_t)M0 * 512 + k0;
#pragma unroll
        for (int s = 0; s < 4; ++s) stage_rows8(Ab, ldsA, wave * 4 + s, lane);
        __syncthreads();
#pragma unroll
        for (int kt = 0; kt < 2; ++kt) {
            short8 af[4], bfr[8];
#pragma unroll
            for (int i = 0; i < 4; ++i)
                af[i] = AFRAG(ldsA, wm * 64 + i * 16 + lr, kt * 4 + lq);
            const u16* Bb = Bt + (size_t)(N0 + wn * 128 + lr) * 512 + k0 + kt * 32 + lq * 8;
#pragma unroll
            for (int j = 0; j < 8; ++j)
                bfr[j] = *(const short8*)(Bb + (size_t)j * 16 * 512);
#pragma unroll
            for (int i = 0; i < 4; ++i)
#pragma unroll
                for (int j = 0; j < 8; ++j)
                    acc[i][j] = __builtin_amdgcn_mfma_f32_16x16x32_bf16(bfr[j], af[i], acc[i][j], 0, 0, 0);
        }
        __syncthreads();
    }

    // gate epilogue: cols fine-interleaved (v,u per 16): pairs p -> j=(2p, 2p+1)
    int colbase = N0 + wn * 128;
    int hbase = colbase >> 1;
    float4 bv4[4], bu4[4], w4[4];
#pragma unroll
    for (int p = 0; p < 4; ++p) {
        int nv = colbase + p * 32 + lq * 4;
        bv4[p] = *(const float4*)&bvu[nv];
        bu4[p] = *(const float4*)&bvu[nv + 16];
        w4[p]  = *(const float4*)&w_attn[hbase + p * 16 + lq * 4];
    }
    float* slab = Araw4 + (size_t)(blockIdx.y * 2 + wn) * ROWS;
#pragma unroll
    for (int i = 0; i < 4; ++i) {
        int m = M0 + wm * 64 + i * 16 + lr;
        float iv = invn[m];
        float part = 0.f;
#pragma unroll
        for (int p = 0; p < 4; ++p) {
#pragma unroll
            for (int r = 0; r < 4; ++r) {
                float v = acc[i][2 * p][r] * iv + (&bv4[p].x)[r];
                float u = acc[i][2 * p + 1][r] * iv + (&bu4[p].x)[r];
                part += tanhf(v) * (&w4[p].x)[r] * (1.0f / (1.0f + expf(-u)));
            }
        }
        part += __shfl_xor(part, 16, 64);
        part += __shfl_xor(part, 32, 64);
        if (lq == 0) slab[m] = part;
    }
}

// ---------------- K5: sum 4 slabs + softmax over N + fuse *invn ----------------
__global__ __launch_bounds__(256) void softmax4_kernel(float* __restrict__ A4,
                                                       const float* __restrict__ invn)
{
    __shared__ float red[256];
    int t = threadIdx.x;
    float* Ab = A4 + (size_t)blockIdx.x * N_;
    const float* ivb = invn + (size_t)blockIdx.x * N_;
    float m = -1e30f;
    for (int i = t; i < N_; i += 256) {
        float s = Ab[i] + Ab[i + ROWS] + Ab[i + 2 * ROWS] + Ab[i + 3 * ROWS];
        Ab[i] = s;
        m = fmaxf(m, s);
    }
    red[t] = m; __syncthreads();
    for (int s = 128; s; s >>= 1) { if (t < s) red[t] = fmaxf(red[t], red[t + s]); __syncthreads(); }
    m = red[0]; __syncthreads();
    float sum = 0.f;
    for (int i = t; i < N_; i += 256) { float e = expf(Ab[i] - m); Ab[i] = e; sum += e; }
    red[t] = sum; __syncthreads();
    for (int s = 128; s; s >>= 1) { if (t < s) red[t] += red[t + s]; __syncthreads(); }
    float inv = 1.0f / red[0];
    for (int i = t; i < N_; i += 256) Ab[i] = Ab[i] * inv * ivb[i];
}

// ---------------- K6: weighted pooling  slide[b] += sum Asc[n]*xpraw[n] ----------------
__global__ __launch_bounds__(256) void pool_kernel(
    const float* __restrict__ Asc, const u16* __restrict__ xpraw, float* __restrict__ slide)
{
    int b = blockIdx.y;
    int t = threadIdx.x;
    size_t base = (size_t)b * N_ + (size_t)blockIdx.x * 64;
    float a0 = 0.f, a1 = 0.f;
#pragma unroll 4
    for (int r = 0; r < 64; ++r) {
        size_t row = base + r;
        float a = Asc[row];
        u32 pk = *(const u32*)&xpraw[row * D_ + 2 * t];
        a0 += a * bf2f((u16)pk);
        a1 += a * bf2f((u16)(pk >> 16));
    }
    atomicAdd(&slide[b * D_ + 2 * t], a0);
    atomicAdd(&slide[b * D_ + 2 * t + 1], a1);
}

// ---------------- K7: finalize ----------------
__global__ __launch_bounds__(512) void finalize_kernel(
    const float* __restrict__ slide_s, const float* __restrict__ slide_l,
    const float* __restrict__ desc, float* __restrict__ out)
{
    __shared__ float txt[4][512];
    __shared__ float ssn[2][512];
    __shared__ float sln[2][512];
    __shared__ float red[512];
    __shared__ float lg[8];
    int t = threadIdx.x;

    auto reduceSum = [&](float v) -> float {
        red[t] = v; __syncthreads();
        for (int s = 256; s; s >>= 1) { if (t < s) red[t] += red[t + s]; __syncthreads(); }
        float r = red[0]; __syncthreads();
        return r;
    };

    for (int c = 0; c < 4; ++c) {
        float m = -1e30f;
        for (int k = 0; k < 8; ++k) m = fmaxf(m, desc[((size_t)c * 8 + k) * 512 + t]);
        float ss = reduceSum(m * m);
        txt[c][t] = m / fmaxf(sqrtf(ss), EPS_);
    }
    for (int b = 0; b < 2; ++b) {
        float v = slide_s[b * 512 + t];
        float ss = reduceSum(v * v);
        ssn[b][t] = v / fmaxf(sqrtf(ss), EPS_);
        v = slide_l[b * 512 + t];
        ss = reduceSum(v * v);
        sln[b][t] = v / fmaxf(sqrtf(ss), EPS_);
    }
    __syncthreads();
    for (int b = 0; b < 2; ++b)
        for (int c = 0; c < 4; ++c) {
            float v = ssn[b][t] * txt[c][t] + sln[b][t] * txt[c][t];
            float s = reduceSum(v);
            if (t == 0) lg[b * 4 + c] = s;
        }
    __syncthreads();
    if (t < 2) {
        int b = t;
        float m = -1e30f;
        for (int c = 0; c < 4; ++c) m = fmaxf(m, lg[b * 4 + c]);
        float e[4]; float den = 0.f;
        for (int c = 0; c < 4; ++c) { e[c] = expf(lg[b * 4 + c] - m); den += e[c]; }
        int am = 0; float bm = -1.f;
        for (int c = 0; c < 4; ++c) {
            float pcl = e[c] / den;
            out[b * 4 + c] = pcl;
            if (pcl > bm) { bm = pcl; am = c; }
        }
        out[8 + b] = (float)am;
    }
}

extern "C" void kernel_launch(void* const* d_in, const int* in_sizes, int n_in,
                              void* d_out, int out_size, void* d_ws, size_t ws_size,
                              hipStream_t stream) {
    const float* x_s    = (const float*)d_in[0];
    const float* x_l    = (const float*)d_in[2];
    const float* W_proj = (const float*)d_in[4];
    const float* b_proj = (const float*)d_in[5];
    const float* desc   = (const float*)d_in[6];
    const float* Wv     = (const float*)d_in[7];
    const float* bv     = (const float*)d_in[8];
    const float* Wu     = (const float*)d_in[9];
    const float* bu     = (const float*)d_in[10];
    const float* w_attn = (const float*)d_in[11];
    float* out = (float*)d_out;

    // workspace layout (bytes):
    //  0        : xn    bf16 [32768x512]  (33554432)
    //  33554432 : xpraw bf16 [32768x512]  (33554432)
    //  67108864 : WpT   bf16 [512x512]    (524288)
    //  67633152 : WvuT  bf16 [512x512]    (524288, fine-interleaved)
    //  68157440 : descF bf16 fragment     (32768)
    //  68190208 : bvu   f32 [512]         (2048)
    //  68192256 : invn  f32 [32768]       (131072)
    //  68323328 : slide_s f32 [2x512]     (4096)
    //  68327424 : slide_l f32 [2x512]     (4096)
    //  68331520 : Araw4 f32 [4x32768]     (524288)   -> ends 68855808 (~68.9MB)
    char* w = (char*)d_ws;
    u16* xn      = (u16*)w;
    u16* xpraw   = (u16*)(w + 33554432);
    u16* WpT     = (u16*)(w + 67108864);
    u16* WvuT    = (u16*)(w + 67633152);
    u16* descF   = (u16*)(w + 68157440);
    float* bvu   = (float*)(w + 68190208);
    float* invn  = (float*)(w + 68192256);
    float* slide_s = (float*)(w + 68323328);
    float* slide_l = (float*)(w + 68327424);
    float* Araw4 = (float*)(w + 68331520);

    hipMemsetAsync(slide_s, 0, 8192, stream);   // slides only; Araw4 fully overwritten
    prep_weights_kernel<<<1024, 256, 0, stream>>>(W_proj, Wv, Wu, bv, bu, desc,
                                                  WpT, WvuT, bvu, descF);

    float* cls_s = out + 10;
    float* cls_l = out + 10 + (size_t)ROWS * C_;

    for (int s = 0; s < 2; ++s) {
        const float* x = s ? x_l : x_s;
        float* cls     = s ? cls_l : cls_s;
        float* slide   = s ? slide_l : slide_s;

        rownorm_cast_kernel<<<ROWS / 4, 256, 0, stream>>>(x, xn);
        gemm_bias_kernel<<<dim3(256, 2), 256, 0, stream>>>(xn, WpT, b_proj, xpraw);
        classscore_kernel<<<256, 256, 0, stream>>>(xpraw, descF, invn, cls);
        gate_kernel<<<dim3(256, 2), 256, 0, stream>>>(xpraw, WvuT, bvu, invn, w_attn, Araw4);
        softmax4_kernel<<<2, 256, 0, stream>>>(Araw4, invn);
        pool_kernel<<<dim3(N_ / 64, 2), 256, 0, stream>>>(Araw4, xpraw, slide);
    }
    finalize_kernel<<<1, 512, 0, stream>>>(slide_s, slide_l, desc, out);
}

// Round 6
// 423.381 us; speedup vs baseline: 1.4383x; 1.2605x over previous
//
#include <hip/hip_runtime.h>
#include <math.h>

#define B_ 2
#define N_ 16384
#define D_ 512
#define C_ 4
#define K_ 8
#define ROWS (B_*N_)   // 32768
#define EPS_ 1e-12f

typedef unsigned short u16;
typedef unsigned int u32;
using short8  = __attribute__((ext_vector_type(8))) short;
using float4v = __attribute__((ext_vector_type(4))) float;

__device__ __forceinline__ u16 f2bf(float f) {
    union { float f; u32 u; } v; v.f = f;
    u32 r = v.u + 0x7fffu + ((v.u >> 16) & 1u);
    return (u16)(r >> 16);
}
__device__ __forceinline__ u32 pack2(float a, float b) {
    return (u32)f2bf(a) | ((u32)f2bf(b) << 16);
}
__device__ __forceinline__ float bf2f(u16 h) {
    union { u32 u; float f; } v; v.u = ((u32)h) << 16;
    return v.f;
}
__device__ __forceinline__ void load_lds16(const u16* g, u16* l) {
    __builtin_amdgcn_global_load_lds(
        (const __attribute__((address_space(1))) u32*)g,
        (__attribute__((address_space(3))) u32*)l, 16, 0, 0);
}
// Stage 8 rows x 64 k (bf16) of a row-major tile (row stride 512 u16) into LDS,
// fully coalesced (each 8-lane group = 128B contiguous), XOR-swizzled so that
// fragment ds_read_b128 is conflict-free. LDS addr(r,c)=r*64 + (c^(r&7))*8 (u16).
__device__ __forceinline__ void stage_rows8(const u16* gtile, u16* ldsTile, int g, int lane) {
    int rg = lane >> 3;                 // row in group 0..7
    int c  = (lane & 7) ^ rg;           // source chunk for stored slot (lane&7)
    load_lds16(gtile + (size_t)(g * 8 + rg) * 512 + c * 8, ldsTile + g * 512);
}
#define AFRAG(lds, R, c) (*(const short8*)&(lds)[(R) * 64 + (((c) ^ ((R) & 7)) * 8)])

// ---------------- P0: weight prep ----------------
__global__ __launch_bounds__(256) void prep_weights_kernel(
    const float* __restrict__ Wp, const float* __restrict__ Wv, const float* __restrict__ Wu,
    const float* __restrict__ bv, const float* __restrict__ bu, const float* __restrict__ desc,
    u16* __restrict__ WpT, u16* __restrict__ WvuT, float* __restrict__ bvu,
    u16* __restrict__ descF)
{
    int idx = blockIdx.x * 256 + threadIdx.x;   // 0 .. 262143
    int n = idx >> 9, k = idx & 511;
    WpT[idx] = f2bf(Wp[k * 512 + n]);
    int tile = n >> 4, pair = tile >> 1, half = tile & 1, h = pair * 16 + (n & 15);
    WvuT[idx] = f2bf(half ? Wu[k * 256 + h] : Wv[k * 256 + h]);
    if (idx < 512) {
        int tl = idx >> 4, pr = tl >> 1, hf = tl & 1, hh = pr * 16 + (idx & 15);
        bvu[idx] = hf ? bu[hh] : bv[hh];
    }
    if (idx < 16384) {
        int j = idx & 7, l = (idx >> 3) & 63, g = (idx >> 9) & 1, kt = idx >> 10;
        descF[idx] = f2bf(desc[(size_t)(g * 16 + (l & 15)) * 512 + kt * 32 + (l >> 4) * 8 + j]);
    }
}

// ---------------- K0: per-row L2-normalize x and cast to bf16 ----------------
__global__ __launch_bounds__(256) void rownorm_cast_kernel(
    const float* __restrict__ x, u16* __restrict__ xn)
{
    int wave = threadIdx.x >> 6, lane = threadIdx.x & 63;
    size_t row = (size_t)blockIdx.x * 4 + wave;
    const float* xr = x + row * D_;
    float4 a = *(const float4*)&xr[lane * 8];
    float4 b = *(const float4*)&xr[lane * 8 + 4];
    float s = a.x*a.x + a.y*a.y + a.z*a.z + a.w*a.w
            + b.x*b.x + b.y*b.y + b.z*b.z + b.w*b.w;
#pragma unroll
    for (int off = 32; off; off >>= 1) s += __shfl_xor(s, off, 64);
    float inv = 1.0f / fmaxf(sqrtf(s), EPS_);
    uint4 o;
    o.x = pack2(a.x * inv, a.y * inv);
    o.y = pack2(a.z * inv, a.w * inv);
    o.z = pack2(b.x * inv, b.y * inv);
    o.w = pack2(b.z * inv, b.w * inv);
    *(uint4*)&xn[row * D_ + lane * 8] = o;
}

// ---------------- K1: GEMM xpraw = xn @ WpT^T + bias ----------------
// Block 128 rows x 256 cols, BK=64; BOTH operands staged (coalesced+swizzled).
// 4 waves (2x2); wave tile 64x128 = acc[4][8]; swapped mfma => C[m..+lr][n..+lq*4+r].
__global__ __launch_bounds__(256, 2) void gemm_bias_kernel(
    const u16* __restrict__ A, const u16* __restrict__ Bt,
    const float* __restrict__ bias, u16* __restrict__ C)
{
    __shared__ u16 ldsA[128 * 64];
    __shared__ u16 ldsB[256 * 64];
    int t = threadIdx.x, wave = t >> 6, lane = t & 63;
    int lr = lane & 15, lq = lane >> 4;
    int wm = wave >> 1, wn = wave & 1;
    int M0 = blockIdx.x * 128, N0 = blockIdx.y * 256;

    float4v acc[4][8];
#pragma unroll
    for (int i = 0; i < 4; ++i)
#pragma unroll
        for (int j = 0; j < 8; ++j)
#pragma unroll
            for (int r = 0; r < 4; ++r) acc[i][j][r] = 0.f;

    for (int k0 = 0; k0 < 512; k0 += 64) {
        const u16* Ab = A  + (size_t)M0 * 512 + k0;
        const u16* Bb = Bt + (size_t)N0 * 512 + k0;
#pragma unroll
        for (int s = 0; s < 4; ++s) stage_rows8(Ab, ldsA, wave * 4 + s, lane);
#pragma unroll
        for (int s = 0; s < 8; ++s) stage_rows8(Bb, ldsB, wave * 8 + s, lane);
        __syncthreads();
#pragma unroll
        for (int kt = 0; kt < 2; ++kt) {
            short8 af[4], bfr[8];
#pragma unroll
            for (int i = 0; i < 4; ++i)
                af[i] = AFRAG(ldsA, wm * 64 + i * 16 + lr, kt * 4 + lq);
#pragma unroll
            for (int j = 0; j < 8; ++j)
                bfr[j] = AFRAG(ldsB, wn * 128 + j * 16 + lr, kt * 4 + lq);
#pragma unroll
            for (int i = 0; i < 4; ++i)
#pragma unroll
                for (int j = 0; j < 8; ++j)
                    acc[i][j] = __builtin_amdgcn_mfma_f32_16x16x32_bf16(bfr[j], af[i], acc[i][j], 0, 0, 0);
        }
        __syncthreads();
    }

    float4 b4[8];
#pragma unroll
    for (int j = 0; j < 8; ++j)
        b4[j] = *(const float4*)&bias[N0 + wn * 128 + j * 16 + lq * 4];
#pragma unroll
    for (int i = 0; i < 4; ++i) {
        int m = M0 + wm * 64 + i * 16 + lr;
        u16* crow = C + (size_t)m * 512;
#pragma unroll
        for (int j = 0; j < 8; ++j) {
            int nb = N0 + wn * 128 + j * 16 + lq * 4;
            uint2 o;
            o.x = pack2(acc[i][j][0] + b4[j].x, acc[i][j][1] + b4[j].y);
            o.y = pack2(acc[i][j][2] + b4[j].z, acc[i][j][3] + b4[j].w);
            *(uint2*)&crow[nb] = o;
        }
    }
}

// ---------------- K2: class scores + row inv-norm (staged A, Gram-diag) ----------------
__global__ __launch_bounds__(256) void classscore_kernel(
    const u16* __restrict__ xpraw, const u16* __restrict__ descF,
    float* __restrict__ invn, float* __restrict__ cls_out)
{
    __shared__ u16 ldsA[128 * 64];
    __shared__ u16 descL[16384];
    __shared__ float sInv[4][2][16];
    int t = threadIdx.x, wave = t >> 6, lane = t & 63;
    int lr = lane & 15, lq = lane >> 4;
    int rows0 = blockIdx.x * 128;

#pragma unroll
    for (int s = 0; s < 8; ++s) {
        int u = wave * 8 + s;
        load_lds16(descF + u * 512 + lane * 8, descL + u * 512);
    }

    float4v accS[2][2], accG[2];
#pragma unroll
    for (int h = 0; h < 2; ++h) {
#pragma unroll
        for (int r = 0; r < 4; ++r) { accS[h][0][r] = 0.f; accS[h][1][r] = 0.f; accG[h][r] = 0.f; }
    }

    for (int k0 = 0; k0 < 512; k0 += 64) {
        const u16* Ab = xpraw + (size_t)rows0 * 512 + k0;
#pragma unroll
        for (int s = 0; s < 4; ++s) stage_rows8(Ab, ldsA, wave * 4 + s, lane);
        __syncthreads();
#pragma unroll
        for (int kt = 0; kt < 2; ++kt) {
            int ktg = (k0 >> 5) + kt;
            short8 d0 = *(const short8*)&descL[(ktg * 2 + 0) * 512 + lane * 8];
            short8 d1 = *(const short8*)&descL[(ktg * 2 + 1) * 512 + lane * 8];
#pragma unroll
            for (int h = 0; h < 2; ++h) {
                short8 af = AFRAG(ldsA, wave * 32 + h * 16 + lr, kt * 4 + lq);
                accS[h][0] = __builtin_amdgcn_mfma_f32_16x16x32_bf16(af, d0, accS[h][0], 0, 0, 0);
                accS[h][1] = __builtin_amdgcn_mfma_f32_16x16x32_bf16(af, d1, accS[h][1], 0, 0, 0);
                accG[h]    = __builtin_amdgcn_mfma_f32_16x16x32_bf16(af, af, accG[h], 0, 0, 0);
            }
        }
        __syncthreads();
    }

#pragma unroll
    for (int h = 0; h < 2; ++h) {
        int base0 = rows0 + wave * 32 + h * 16;
#pragma unroll
        for (int r = 0; r < 4; ++r) {
            if (lr == lq * 4 + r) {
                float iv = 1.0f / fmaxf(sqrtf(accG[h][r]), EPS_);
                sInv[wave][h][lq * 4 + r] = iv;
                invn[base0 + lq * 4 + r] = iv;
            }
        }
    }
    __syncthreads();
    const float scale = 0.04419417382415922f;   // 512^-0.5
#pragma unroll
    for (int h = 0; h < 2; ++h) {
        int base0 = rows0 + wave * 32 + h * 16;
#pragma unroll
        for (int r = 0; r < 4; ++r) {
            int row = base0 + lq * 4 + r;
            float iv = sInv[wave][h][lq * 4 + r];
            float sv0 = accS[h][0][r] * iv, sv1 = accS[h][1][r] * iv;
#pragma unroll
            for (int g = 0; g < 2; ++g) {
                float s = g ? sv1 : sv0;
                float ts = s * scale;
                float mx = ts;
                mx = fmaxf(mx, __shfl_xor(mx, 1, 64));
                mx = fmaxf(mx, __shfl_xor(mx, 2, 64));
                mx = fmaxf(mx, __shfl_xor(mx, 4, 64));
                float e = expf(ts - mx);
                float num = e * s, den = e;
                num += __shfl_xor(num, 1, 64); den += __shfl_xor(den, 1, 64);
                num += __shfl_xor(num, 2, 64); den += __shfl_xor(den, 2, 64);
                num += __shfl_xor(num, 4, 64); den += __shfl_xor(den, 4, 64);
                if ((lr & 7) == 0) {
                    int c = g * 2 + ((lr >> 3) & 1);
                    cls_out[(size_t)row * 4 + c] = num / den;
                }
            }
        }
    }
}

// ---------------- K3: GEMM2 + in-register gated attention, partials to 4 slabs ----
__global__ __launch_bounds__(256, 2) void gate_kernel(
    const u16* __restrict__ A, const u16* __restrict__ Bt,
    const float* __restrict__ bvu, const float* __restrict__ invn,
    const float* __restrict__ w_attn, float* __restrict__ Araw4)
{
    __shared__ u16 ldsA[128 * 64];
    __shared__ u16 ldsB[256 * 64];
    int t = threadIdx.x, wave = t >> 6, lane = t & 63;
    int lr = lane & 15, lq = lane >> 4;
    int wm = wave >> 1, wn = wave & 1;
    int M0 = blockIdx.x * 128, N0 = blockIdx.y * 256;

    float4v acc[4][8];
#pragma unroll
    for (int i = 0; i < 4; ++i)
#pragma unroll
        for (int j = 0; j < 8; ++j)
#pragma unroll
            for (int r = 0; r < 4; ++r) acc[i][j][r] = 0.f;

    for (int k0 = 0; k0 < 512; k0 += 64) {
        const u16* Ab = A  + (size_t)M0 * 512 + k0;
        const u16* Bb = Bt + (size_t)N0 * 512 + k0;
#pragma unroll
        for (int s = 0; s < 4; ++s) stage_rows8(Ab, ldsA, wave * 4 + s, lane);
#pragma unroll
        for (int s = 0; s < 8; ++s) stage_rows8(Bb, ldsB, wave * 8 + s, lane);
        __syncthreads();
#pragma unroll
        for (int kt = 0; kt < 2; ++kt) {
            short8 af[4], bfr[8];
#pragma unroll
            for (int i = 0; i < 4; ++i)
                af[i] = AFRAG(ldsA, wm * 64 + i * 16 + lr, kt * 4 + lq);
#pragma unroll
            for (int j = 0; j < 8; ++j)
                bfr[j] = AFRAG(ldsB, wn * 128 + j * 16 + lr, kt * 4 + lq);
#pragma unroll
            for (int i = 0; i < 4; ++i)
#pragma unroll
                for (int j = 0; j < 8; ++j)
                    acc[i][j] = __builtin_amdgcn_mfma_f32_16x16x32_bf16(bfr[j], af[i], acc[i][j], 0, 0, 0);
        }
        __syncthreads();
    }

    // gate epilogue: cols fine-interleaved (16 v | 16 u per 32-col pair)
    int colbase = N0 + wn * 128;
    int hbase = colbase >> 1;
    float4 bv4[4], bu4[4], w4[4];
#pragma unroll
    for (int p = 0; p < 4; ++p) {
        int nv = colbase + p * 32 + lq * 4;
        bv4[p] = *(const float4*)&bvu[nv];
        bu4[p] = *(const float4*)&bvu[nv + 16];
        w4[p]  = *(const float4*)&w_attn[hbase + p * 16 + lq * 4];
    }
    float* slab = Araw4 + (size_t)(blockIdx.y * 2 + wn) * ROWS;
#pragma unroll
    for (int i = 0; i < 4; ++i) {
        int m = M0 + wm * 64 + i * 16 + lr;
        float iv = invn[m];
        float part = 0.f;
#pragma unroll
        for (int p = 0; p < 4; ++p) {
#pragma unroll
            for (int r = 0; r < 4; ++r) {
                float v = acc[i][2 * p][r] * iv + (&bv4[p].x)[r];
                float u = acc[i][2 * p + 1][r] * iv + (&bu4[p].x)[r];
                part += tanhf(v) * (&w4[p].x)[r] * (1.0f / (1.0f + expf(-u)));
            }
        }
        part += __shfl_xor(part, 16, 64);
        part += __shfl_xor(part, 32, 64);
        if (lq == 0) slab[m] = part;
    }
}

// ---------------- K5: sum 4 slabs + softmax over N + fuse *invn ----------------
__global__ __launch_bounds__(256) void softmax4_kernel(float* __restrict__ A4,
                                                       const float* __restrict__ invn)
{
    __shared__ float red[256];
    int t = threadIdx.x;
    float* Ab = A4 + (size_t)blockIdx.x * N_;
    const float* ivb = invn + (size_t)blockIdx.x * N_;
    float m = -1e30f;
    for (int i = t; i < N_; i += 256) {
        float s = Ab[i] + Ab[i + ROWS] + Ab[i + 2 * ROWS] + Ab[i + 3 * ROWS];
        Ab[i] = s;
        m = fmaxf(m, s);
    }
    red[t] = m; __syncthreads();
    for (int s = 128; s; s >>= 1) { if (t < s) red[t] = fmaxf(red[t], red[t + s]); __syncthreads(); }
    m = red[0]; __syncthreads();
    float sum = 0.f;
    for (int i = t; i < N_; i += 256) { float e = expf(Ab[i] - m); Ab[i] = e; sum += e; }
    red[t] = sum; __syncthreads();
    for (int s = 128; s; s >>= 1) { if (t < s) red[t] += red[t + s]; __syncthreads(); }
    float inv = 1.0f / red[0];
    for (int i = t; i < N_; i += 256) Ab[i] = Ab[i] * inv * ivb[i];
}

// ---------------- K6: pooling, full-row uint4 loads + LDS combine ----------------
// grid (64, B_); block 256 = 4 waves; block covers 256 rows; wave w rows w,w+4,...
__global__ __launch_bounds__(256) void pool_kernel(
    const float* __restrict__ Asc, const u16* __restrict__ xpraw, float* __restrict__ slide)
{
    __shared__ float lds[4][512];
    int t = threadIdx.x, wave = t >> 6, lane = t & 63;
    int b = blockIdx.y;
    size_t row0 = (size_t)b * N_ + (size_t)blockIdx.x * 256 + wave;
    float a[8] = {};
    for (int r = 0; r < 64; ++r) {
        size_t row = row0 + r * 4;
        float av = Asc[row];
        uint4 pk = *(const uint4*)&xpraw[row * D_ + lane * 8];
        a[0] += av * bf2f((u16)pk.x); a[1] += av * bf2f((u16)(pk.x >> 16));
        a[2] += av * bf2f((u16)pk.y); a[3] += av * bf2f((u16)(pk.y >> 16));
        a[4] += av * bf2f((u16)pk.z); a[5] += av * bf2f((u16)(pk.z >> 16));
        a[6] += av * bf2f((u16)pk.w); a[7] += av * bf2f((u16)(pk.w >> 16));
    }
#pragma unroll
    for (int i = 0; i < 8; ++i) lds[wave][lane * 8 + i] = a[i];
    __syncthreads();
    // 256 threads, 2 cols each
#pragma unroll
    for (int q = 0; q < 2; ++q) {
        int c = t * 2 + q;
        float s = lds[0][c] + lds[1][c] + lds[2][c] + lds[3][c];
        atomicAdd(&slide[b * D_ + c], s);
    }
}

// ---------------- K7: finalize ----------------
__global__ __launch_bounds__(512) void finalize_kernel(
    const float* __restrict__ slide_s, const float* __restrict__ slide_l,
    const float* __restrict__ desc, float* __restrict__ out)
{
    __shared__ float txt[4][512];
    __shared__ float ssn[2][512];
    __shared__ float sln[2][512];
    __shared__ float red[512];
    __shared__ float lg[8];
    int t = threadIdx.x;

    auto reduceSum = [&](float v) -> float {
        red[t] = v; __syncthreads();
        for (int s = 256; s; s >>= 1) { if (t < s) red[t] += red[t + s]; __syncthreads(); }
        float r = red[0]; __syncthreads();
        return r;
    };

    for (int c = 0; c < 4; ++c) {
        float m = -1e30f;
        for (int k = 0; k < 8; ++k) m = fmaxf(m, desc[((size_t)c * 8 + k) * 512 + t]);
        float ss = reduceSum(m * m);
        txt[c][t] = m / fmaxf(sqrtf(ss), EPS_);
    }
    for (int b = 0; b < 2; ++b) {
        float v = slide_s[b * 512 + t];
        float ss = reduceSum(v * v);
        ssn[b][t] = v / fmaxf(sqrtf(ss), EPS_);
        v = slide_l[b * 512 + t];
        ss = reduceSum(v * v);
        sln[b][t] = v / fmaxf(sqrtf(ss), EPS_);
    }
    __syncthreads();
    for (int b = 0; b < 2; ++b)
        for (int c = 0; c < 4; ++c) {
            float v = ssn[b][t] * txt[c][t] + sln[b][t] * txt[c][t];
            float s = reduceSum(v);
            if (t == 0) lg[b * 4 + c] = s;
        }
    __syncthreads();
    if (t < 2) {
        int b = t;
        float m = -1e30f;
        for (int c = 0; c < 4; ++c) m = fmaxf(m, lg[b * 4 + c]);
        float e[4]; float den = 0.f;
        for (int c = 0; c < 4; ++c) { e[c] = expf(lg[b * 4 + c] - m); den += e[c]; }
        int am = 0; float bm = -1.f;
        for (int c = 0; c < 4; ++c) {
            float pcl = e[c] / den;
            out[b * 4 + c] = pcl;
            if (pcl > bm) { bm = pcl; am = c; }
        }
        out[8 + b] = (float)am;
    }
}

extern "C" void kernel_launch(void* const* d_in, const int* in_sizes, int n_in,
                              void* d_out, int out_size, void* d_ws, size_t ws_size,
                              hipStream_t stream) {
    const float* x_s    = (const float*)d_in[0];
    const float* x_l    = (const float*)d_in[2];
    const float* W_proj = (const float*)d_in[4];
    const float* b_proj = (const float*)d_in[5];
    const float* desc   = (const float*)d_in[6];
    const float* Wv     = (const float*)d_in[7];
    const float* bv     = (const float*)d_in[8];
    const float* Wu     = (const float*)d_in[9];
    const float* bu     = (const float*)d_in[10];
    const float* w_attn = (const float*)d_in[11];
    float* out = (float*)d_out;

    // workspace layout (bytes):
    //  0        : xn    bf16 [32768x512]  (33554432)
    //  33554432 : xpraw bf16 [32768x512]  (33554432)
    //  67108864 : WpT   bf16 [512x512]    (524288)
    //  67633152 : WvuT  bf16 [512x512]    (524288, fine-interleaved)
    //  68157440 : descF bf16 fragment     (32768)
    //  68190208 : bvu   f32 [512]         (2048)
    //  68192256 : invn  f32 [32768]       (131072)
    //  68323328 : slide_s f32 [2x512]     (4096)
    //  68327424 : slide_l f32 [2x512]     (4096)
    //  68331520 : Araw4 f32 [4x32768]     (524288)
    char* w = (char*)d_ws;
    u16* xn      = (u16*)w;
    u16* xpraw   = (u16*)(w + 33554432);
    u16* WpT     = (u16*)(w + 67108864);
    u16* WvuT    = (u16*)(w + 67633152);
    u16* descF   = (u16*)(w + 68157440);
    float* bvu   = (float*)(w + 68190208);
    float* invn  = (float*)(w + 68192256);
    float* slide_s = (float*)(w + 68323328);
    float* slide_l = (float*)(w + 68327424);
    float* Araw4 = (float*)(w + 68331520);

    hipMemsetAsync(slide_s, 0, 8192, stream);   // slides only; Araw4 fully overwritten
    prep_weights_kernel<<<1024, 256, 0, stream>>>(W_proj, Wv, Wu, bv, bu, desc,
                                                  WpT, WvuT, bvu, descF);

    float* cls_s = out + 10;
    float* cls_l = out + 10 + (size_t)ROWS * C_;

    for (int s = 0; s < 2; ++s) {
        const float* x = s ? x_l : x_s;
        float* cls     = s ? cls_l : cls_s;
        float* slide   = s ? slide_l : slide_s;

        rownorm_cast_kernel<<<ROWS / 4, 256, 0, stream>>>(x, xn);
        gemm_bias_kernel<<<dim3(256, 2), 256, 0, stream>>>(xn, WpT, b_proj, xpraw);
        classscore_kernel<<<256, 256, 0, stream>>>(xpraw, descF, invn, cls);
        gate_kernel<<<dim3(256, 2), 256, 0, stream>>>(xpraw, WvuT, bvu, invn, w_attn, Araw4);
        softmax4_kernel<<<2, 256, 0, stream>>>(Araw4, invn);
        pool_kernel<<<dim3(64, 2), 256, 0, stream>>>(Araw4, xpraw, slide);
    }
    finalize_kernel<<<1, 512, 0, stream>>>(slide_s, slide_l, desc, out);
}

// Round 7
// 359.582 us; speedup vs baseline: 1.6934x; 1.1774x over previous
//
#include <hip/hip_runtime.h>
#include <math.h>

#define B_ 2
#define N_ 16384
#define D_ 512
#define C_ 4
#define K_ 8
#define ROWS (B_*N_)   // 32768
#define EPS_ 1e-12f

typedef unsigned short u16;
typedef unsigned int u32;
using short8  = __attribute__((ext_vector_type(8))) short;
using float4v = __attribute__((ext_vector_type(4))) float;

__device__ __forceinline__ u16 f2bf(float f) {
    union { float f; u32 u; } v; v.f = f;
    u32 r = v.u + 0x7fffu + ((v.u >> 16) & 1u);
    return (u16)(r >> 16);
}
__device__ __forceinline__ u32 pack2(float a, float b) {
    return (u32)f2bf(a) | ((u32)f2bf(b) << 16);
}
__device__ __forceinline__ float bf2f(u16 h) {
    union { u32 u; float f; } v; v.u = ((u32)h) << 16;
    return v.f;
}
__device__ __forceinline__ void load_lds16(const u16* g, u16* l) {
    __builtin_amdgcn_global_load_lds(
        (const __attribute__((address_space(1))) u32*)g,
        (__attribute__((address_space(3))) u32*)l, 16, 0, 0);
}
// Stage 8 rows x 64 k (bf16) of a row-major tile (row stride 512 u16) into LDS,
// fully coalesced, XOR-swizzled. LDS addr(r,c)=r*64 + (c^(r&7))*8 (u16).
__device__ __forceinline__ void stage_rows8(const u16* gtile, u16* ldsTile, int g, int lane) {
    int rg = lane >> 3;
    int c  = (lane & 7) ^ rg;
    load_lds16(gtile + (size_t)(g * 8 + rg) * 512 + c * 8, ldsTile + g * 512);
}
#define AFRAG(lds, R, c) (*(const short8*)&(lds)[(R) * 64 + (((c) ^ ((R) & 7)) * 8)])

// ---------------- P0: weight prep ----------------
__global__ __launch_bounds__(256) void prep_weights_kernel(
    const float* __restrict__ Wp, const float* __restrict__ Wv, const float* __restrict__ Wu,
    const float* __restrict__ bv, const float* __restrict__ bu, const float* __restrict__ desc,
    u16* __restrict__ WpT, u16* __restrict__ WvuT, float* __restrict__ bvu,
    u16* __restrict__ descF)
{
    int idx = blockIdx.x * 256 + threadIdx.x;   // 0 .. 262143
    int n = idx >> 9, k = idx & 511;
    WpT[idx] = f2bf(Wp[k * 512 + n]);
    int tile = n >> 4, pair = tile >> 1, half = tile & 1, h = pair * 16 + (n & 15);
    WvuT[idx] = f2bf(half ? Wu[k * 256 + h] : Wv[k * 256 + h]);
    if (idx < 512) {
        int tl = idx >> 4, pr = tl >> 1, hf = tl & 1, hh = pr * 16 + (idx & 15);
        bvu[idx] = hf ? bu[hh] : bv[hh];
    }
    if (idx < 16384) {
        int j = idx & 7, l = (idx >> 3) & 63, g = (idx >> 9) & 1, kt = idx >> 10;
        descF[idx] = f2bf(desc[(size_t)(g * 16 + (l & 15)) * 512 + kt * 32 + (l >> 4) * 8 + j]);
    }
}

// ---------------- K0: per-row L2-normalize x and cast to bf16 ----------------
__global__ __launch_bounds__(256) void rownorm_cast_kernel(
    const float* __restrict__ x, u16* __restrict__ xn)
{
    int wave = threadIdx.x >> 6, lane = threadIdx.x & 63;
    size_t row = (size_t)blockIdx.x * 4 + wave;
    const float* xr = x + row * D_;
    float4 a = *(const float4*)&xr[lane * 8];
    float4 b = *(const float4*)&xr[lane * 8 + 4];
    float s = a.x*a.x + a.y*a.y + a.z*a.z + a.w*a.w
            + b.x*b.x + b.y*b.y + b.z*b.z + b.w*b.w;
#pragma unroll
    for (int off = 32; off; off >>= 1) s += __shfl_xor(s, off, 64);
    float inv = 1.0f / fmaxf(sqrtf(s), EPS_);
    uint4 o;
    o.x = pack2(a.x * inv, a.y * inv);
    o.y = pack2(a.z * inv, a.w * inv);
    o.z = pack2(b.x * inv, b.y * inv);
    o.w = pack2(b.z * inv, b.w * inv);
    *(uint4*)&xn[row * D_ + lane * 8] = o;
}

// ---------------- K1: GEMM xpraw = xn @ WpT^T + bias ----------------
__global__ __launch_bounds__(256, 2) void gemm_bias_kernel(
    const u16* __restrict__ A, const u16* __restrict__ Bt,
    const float* __restrict__ bias, u16* __restrict__ C)
{
    __shared__ u16 ldsA[128 * 64];
    __shared__ u16 ldsB[256 * 64];
    int t = threadIdx.x, wave = t >> 6, lane = t & 63;
    int lr = lane & 15, lq = lane >> 4;
    int wm = wave >> 1, wn = wave & 1;
    int M0 = blockIdx.x * 128, N0 = blockIdx.y * 256;

    float4v acc[4][8];
#pragma unroll
    for (int i = 0; i < 4; ++i)
#pragma unroll
        for (int j = 0; j < 8; ++j)
#pragma unroll
            for (int r = 0; r < 4; ++r) acc[i][j][r] = 0.f;

    for (int k0 = 0; k0 < 512; k0 += 64) {
        const u16* Ab = A  + (size_t)M0 * 512 + k0;
        const u16* Bb = Bt + (size_t)N0 * 512 + k0;
#pragma unroll
        for (int s = 0; s < 4; ++s) stage_rows8(Ab, ldsA, wave * 4 + s, lane);
#pragma unroll
        for (int s = 0; s < 8; ++s) stage_rows8(Bb, ldsB, wave * 8 + s, lane);
        __syncthreads();
#pragma unroll
        for (int kt = 0; kt < 2; ++kt) {
            short8 af[4], bfr[8];
#pragma unroll
            for (int i = 0; i < 4; ++i)
                af[i] = AFRAG(ldsA, wm * 64 + i * 16 + lr, kt * 4 + lq);
#pragma unroll
            for (int j = 0; j < 8; ++j)
                bfr[j] = AFRAG(ldsB, wn * 128 + j * 16 + lr, kt * 4 + lq);
#pragma unroll
            for (int i = 0; i < 4; ++i)
#pragma unroll
                for (int j = 0; j < 8; ++j)
                    acc[i][j] = __builtin_amdgcn_mfma_f32_16x16x32_bf16(bfr[j], af[i], acc[i][j], 0, 0, 0);
        }
        __syncthreads();
    }

    float4 b4[8];
#pragma unroll
    for (int j = 0; j < 8; ++j)
        b4[j] = *(const float4*)&bias[N0 + wn * 128 + j * 16 + lq * 4];
#pragma unroll
    for (int i = 0; i < 4; ++i) {
        int m = M0 + wm * 64 + i * 16 + lr;
        u16* crow = C + (size_t)m * 512;
#pragma unroll
        for (int j = 0; j < 8; ++j) {
            int nb = N0 + wn * 128 + j * 16 + lq * 4;
            uint2 o;
            o.x = pack2(acc[i][j][0] + b4[j].x, acc[i][j][1] + b4[j].y);
            o.y = pack2(acc[i][j][2] + b4[j].z, acc[i][j][3] + b4[j].w);
            *(uint2*)&crow[nb] = o;
        }
    }
}

// ---------------- K2: class scores + row inv-norm (staged A, Gram-diag) ----------------
__global__ __launch_bounds__(256) void classscore_kernel(
    const u16* __restrict__ xpraw, const u16* __restrict__ descF,
    float* __restrict__ invn, float* __restrict__ cls_out)
{
    __shared__ u16 ldsA[128 * 64];
    __shared__ u16 descL[16384];
    __shared__ float sInv[4][2][16];
    int t = threadIdx.x, wave = t >> 6, lane = t & 63;
    int lr = lane & 15, lq = lane >> 4;
    int rows0 = blockIdx.x * 128;

#pragma unroll
    for (int s = 0; s < 8; ++s) {
        int u = wave * 8 + s;
        load_lds16(descF + u * 512 + lane * 8, descL + u * 512);
    }

    float4v accS[2][2], accG[2];
#pragma unroll
    for (int h = 0; h < 2; ++h) {
#pragma unroll
        for (int r = 0; r < 4; ++r) { accS[h][0][r] = 0.f; accS[h][1][r] = 0.f; accG[h][r] = 0.f; }
    }

    for (int k0 = 0; k0 < 512; k0 += 64) {
        const u16* Ab = xpraw + (size_t)rows0 * 512 + k0;
#pragma unroll
        for (int s = 0; s < 4; ++s) stage_rows8(Ab, ldsA, wave * 4 + s, lane);
        __syncthreads();
#pragma unroll
        for (int kt = 0; kt < 2; ++kt) {
            int ktg = (k0 >> 5) + kt;
            short8 d0 = *(const short8*)&descL[(ktg * 2 + 0) * 512 + lane * 8];
            short8 d1 = *(const short8*)&descL[(ktg * 2 + 1) * 512 + lane * 8];
#pragma unroll
            for (int h = 0; h < 2; ++h) {
                short8 af = AFRAG(ldsA, wave * 32 + h * 16 + lr, kt * 4 + lq);
                accS[h][0] = __builtin_amdgcn_mfma_f32_16x16x32_bf16(af, d0, accS[h][0], 0, 0, 0);
                accS[h][1] = __builtin_amdgcn_mfma_f32_16x16x32_bf16(af, d1, accS[h][1], 0, 0, 0);
                accG[h]    = __builtin_amdgcn_mfma_f32_16x16x32_bf16(af, af, accG[h], 0, 0, 0);
            }
        }
        __syncthreads();
    }

#pragma unroll
    for (int h = 0; h < 2; ++h) {
        int base0 = rows0 + wave * 32 + h * 16;
#pragma unroll
        for (int r = 0; r < 4; ++r) {
            if (lr == lq * 4 + r) {
                float iv = 1.0f / fmaxf(sqrtf(accG[h][r]), EPS_);
                sInv[wave][h][lq * 4 + r] = iv;
                invn[base0 + lq * 4 + r] = iv;
            }
        }
    }
    __syncthreads();
    const float scale = 0.04419417382415922f;   // 512^-0.5
#pragma unroll
    for (int h = 0; h < 2; ++h) {
        int base0 = rows0 + wave * 32 + h * 16;
#pragma unroll
        for (int r = 0; r < 4; ++r) {
            int row = base0 + lq * 4 + r;
            float iv = sInv[wave][h][lq * 4 + r];
            float sv0 = accS[h][0][r] * iv, sv1 = accS[h][1][r] * iv;
#pragma unroll
            for (int g = 0; g < 2; ++g) {
                float s = g ? sv1 : sv0;
                float ts = s * scale;
                float mx = ts;
                mx = fmaxf(mx, __shfl_xor(mx, 1, 64));
                mx = fmaxf(mx, __shfl_xor(mx, 2, 64));
                mx = fmaxf(mx, __shfl_xor(mx, 4, 64));
                float e = expf(ts - mx);
                float num = e * s, den = e;
                num += __shfl_xor(num, 1, 64); den += __shfl_xor(den, 1, 64);
                num += __shfl_xor(num, 2, 64); den += __shfl_xor(den, 2, 64);
                num += __shfl_xor(num, 4, 64); den += __shfl_xor(den, 4, 64);
                if ((lr & 7) == 0) {
                    int c = g * 2 + ((lr >> 3) & 1);
                    cls_out[(size_t)row * 4 + c] = num / den;
                }
            }
        }
    }
}

// ---------------- K3: GEMM2 + in-register gated attention, partials to 4 slabs ----
__global__ __launch_bounds__(256, 2) void gate_kernel(
    const u16* __restrict__ A, const u16* __restrict__ Bt,
    const float* __restrict__ bvu, const float* __restrict__ invn,
    const float* __restrict__ w_attn, float* __restrict__ Araw4)
{
    __shared__ u16 ldsA[128 * 64];
    __shared__ u16 ldsB[256 * 64];
    int t = threadIdx.x, wave = t >> 6, lane = t & 63;
    int lr = lane & 15, lq = lane >> 4;
    int wm = wave >> 1, wn = wave & 1;
    int M0 = blockIdx.x * 128, N0 = blockIdx.y * 256;

    float4v acc[4][8];
#pragma unroll
    for (int i = 0; i < 4; ++i)
#pragma unroll
        for (int j = 0; j < 8; ++j)
#pragma unroll
            for (int r = 0; r < 4; ++r) acc[i][j][r] = 0.f;

    for (int k0 = 0; k0 < 512; k0 += 64) {
        const u16* Ab = A  + (size_t)M0 * 512 + k0;
        const u16* Bb = Bt + (size_t)N0 * 512 + k0;
#pragma unroll
        for (int s = 0; s < 4; ++s) stage_rows8(Ab, ldsA, wave * 4 + s, lane);
#pragma unroll
        for (int s = 0; s < 8; ++s) stage_rows8(Bb, ldsB, wave * 8 + s, lane);
        __syncthreads();
#pragma unroll
        for (int kt = 0; kt < 2; ++kt) {
            short8 af[4], bfr[8];
#pragma unroll
            for (int i = 0; i < 4; ++i)
                af[i] = AFRAG(ldsA, wm * 64 + i * 16 + lr, kt * 4 + lq);
#pragma unroll
            for (int j = 0; j < 8; ++j)
                bfr[j] = AFRAG(ldsB, wn * 128 + j * 16 + lr, kt * 4 + lq);
#pragma unroll
            for (int i = 0; i < 4; ++i)
#pragma unroll
                for (int j = 0; j < 8; ++j)
                    acc[i][j] = __builtin_amdgcn_mfma_f32_16x16x32_bf16(bfr[j], af[i], acc[i][j], 0, 0, 0);
        }
        __syncthreads();
    }

    int colbase = N0 + wn * 128;
    int hbase = colbase >> 1;
    float4 bv4[4], bu4[4], w4[4];
#pragma unroll
    for (int p = 0; p < 4; ++p) {
        int nv = colbase + p * 32 + lq * 4;
        bv4[p] = *(const float4*)&bvu[nv];
        bu4[p] = *(const float4*)&bvu[nv + 16];
        w4[p]  = *(const float4*)&w_attn[hbase + p * 16 + lq * 4];
    }
    float* slab = Araw4 + (size_t)(blockIdx.y * 2 + wn) * ROWS;
#pragma unroll
    for (int i = 0; i < 4; ++i) {
        int m = M0 + wm * 64 + i * 16 + lr;
        float iv = invn[m];
        float part = 0.f;
#pragma unroll
        for (int p = 0; p < 4; ++p) {
#pragma unroll
            for (int r = 0; r < 4; ++r) {
                float v = acc[i][2 * p][r] * iv + (&bv4[p].x)[r];
                float u = acc[i][2 * p + 1][r] * iv + (&bu4[p].x)[r];
                part += tanhf(v) * (&w4[p].x)[r] * (1.0f / (1.0f + expf(-u)));
            }
        }
        part += __shfl_xor(part, 16, 64);
        part += __shfl_xor(part, 32, 64);
        if (lq == 0) slab[m] = part;
    }
}

// ---------------- K5a: slab-sum + per-block (max, expsum) partials ----------------
// grid (32, B_), 256 thr; block covers 512 rows of batch b. Writes combined Araw in slab0.
__global__ __launch_bounds__(256) void areduce_kernel(
    float* __restrict__ Araw4, float* __restrict__ part)
{
    __shared__ float red[256];
    int t = threadIdx.x, b = blockIdx.y;
    size_t i0 = (size_t)b * N_ + blockIdx.x * 512 + t * 2;
    float v0 = Araw4[i0]     + Araw4[i0 + ROWS]     + Araw4[i0 + 2*ROWS]     + Araw4[i0 + 3*ROWS];
    float v1 = Araw4[i0 + 1] + Araw4[i0 + 1 + ROWS] + Araw4[i0 + 1 + 2*ROWS] + Araw4[i0 + 1 + 3*ROWS];
    *(float2*)&Araw4[i0] = make_float2(v0, v1);
    red[t] = fmaxf(v0, v1); __syncthreads();
    for (int s = 128; s; s >>= 1) { if (t < s) red[t] = fmaxf(red[t], red[t + s]); __syncthreads(); }
    float m = red[0]; __syncthreads();
    red[t] = __expf(v0 - m) + __expf(v1 - m); __syncthreads();
    for (int s = 128; s; s >>= 1) { if (t < s) red[t] += red[t + s]; __syncthreads(); }
    if (t == 0) {
        int pi = b * 32 + blockIdx.x;
        part[pi * 2] = m;
        part[pi * 2 + 1] = red[0];
    }
}

// ---------------- K5b: combine 32 partials per batch -> mg[b], isg[b] ----------------
__global__ __launch_bounds__(64) void acombine_kernel(
    const float* __restrict__ part, float* __restrict__ mg)
{
    int lane = threadIdx.x;           // 0..63, one wave
    int b = lane >> 5, j = lane & 31;
    float m = part[(b * 32 + j) * 2];
    float s = part[(b * 32 + j) * 2 + 1];
    float mm = m;
#pragma unroll
    for (int off = 1; off < 32; off <<= 1) mm = fmaxf(mm, __shfl_xor(mm, off, 64));
    float sc = s * __expf(m - mm);
#pragma unroll
    for (int off = 1; off < 32; off <<= 1) sc += __shfl_xor(sc, off, 64);
    if (j == 0) {
        mg[b * 2] = mm;
        mg[b * 2 + 1] = 1.0f / sc;
    }
}

// ---------------- K6: pooling with inline softmax normalize ----------------
// grid (64, B_); block 256 = 4 waves; block covers 256 rows; wave w rows w,w+4,...
__global__ __launch_bounds__(256) void pool_kernel(
    const float* __restrict__ Araw, const float* __restrict__ invn,
    const float* __restrict__ mg, const u16* __restrict__ xpraw,
    float* __restrict__ slide)
{
    __shared__ float lds[4][512];
    int t = threadIdx.x, wave = t >> 6, lane = t & 63;
    int b = blockIdx.y;
    float m = mg[b * 2], is = mg[b * 2 + 1];
    size_t row0 = (size_t)b * N_ + (size_t)blockIdx.x * 256 + wave;
    float a[8] = {};
    for (int r = 0; r < 64; ++r) {
        size_t row = row0 + r * 4;
        float av = __expf(Araw[row] - m) * is * invn[row];
        uint4 pk = *(const uint4*)&xpraw[row * D_ + lane * 8];
        a[0] += av * bf2f((u16)pk.x); a[1] += av * bf2f((u16)(pk.x >> 16));
        a[2] += av * bf2f((u16)pk.y); a[3] += av * bf2f((u16)(pk.y >> 16));
        a[4] += av * bf2f((u16)pk.z); a[5] += av * bf2f((u16)(pk.z >> 16));
        a[6] += av * bf2f((u16)pk.w); a[7] += av * bf2f((u16)(pk.w >> 16));
    }
#pragma unroll
    for (int i = 0; i < 8; ++i) lds[wave][lane * 8 + i] = a[i];
    __syncthreads();
#pragma unroll
    for (int q = 0; q < 2; ++q) {
        int c = t * 2 + q;
        float s = lds[0][c] + lds[1][c] + lds[2][c] + lds[3][c];
        atomicAdd(&slide[b * D_ + c], s);
    }
}

// ---------------- K7: finalize ----------------
__global__ __launch_bounds__(512) void finalize_kernel(
    const float* __restrict__ slide_s, const float* __restrict__ slide_l,
    const float* __restrict__ desc, float* __restrict__ out)
{
    __shared__ float txt[4][512];
    __shared__ float ssn[2][512];
    __shared__ float sln[2][512];
    __shared__ float red[512];
    __shared__ float lg[8];
    int t = threadIdx.x;

    auto reduceSum = [&](float v) -> float {
        red[t] = v; __syncthreads();
        for (int s = 256; s; s >>= 1) { if (t < s) red[t] += red[t + s]; __syncthreads(); }
        float r = red[0]; __syncthreads();
        return r;
    };

    for (int c = 0; c < 4; ++c) {
        float m = -1e30f;
        for (int k = 0; k < 8; ++k) m = fmaxf(m, desc[((size_t)c * 8 + k) * 512 + t]);
        float ss = reduceSum(m * m);
        txt[c][t] = m / fmaxf(sqrtf(ss), EPS_);
    }
    for (int b = 0; b < 2; ++b) {
        float v = slide_s[b * 512 + t];
        float ss = reduceSum(v * v);
        ssn[b][t] = v / fmaxf(sqrtf(ss), EPS_);
        v = slide_l[b * 512 + t];
        ss = reduceSum(v * v);
        sln[b][t] = v / fmaxf(sqrtf(ss), EPS_);
    }
    __syncthreads();
    for (int b = 0; b < 2; ++b)
        for (int c = 0; c < 4; ++c) {
            float v = ssn[b][t] * txt[c][t] + sln[b][t] * txt[c][t];
            float s = reduceSum(v);
            if (t == 0) lg[b * 4 + c] = s;
        }
    __syncthreads();
    if (t < 2) {
        int b = t;
        float m = -1e30f;
        for (int c = 0; c < 4; ++c) m = fmaxf(m, lg[b * 4 + c]);
        float e[4]; float den = 0.f;
        for (int c = 0; c < 4; ++c) { e[c] = expf(lg[b * 4 + c] - m); den += e[c]; }
        int am = 0; float bm = -1.f;
        for (int c = 0; c < 4; ++c) {
            float pcl = e[c] / den;
            out[b * 4 + c] = pcl;
            if (pcl > bm) { bm = pcl; am = c; }
        }
        out[8 + b] = (float)am;
    }
}

extern "C" void kernel_launch(void* const* d_in, const int* in_sizes, int n_in,
                              void* d_out, int out_size, void* d_ws, size_t ws_size,
                              hipStream_t stream) {
    const float* x_s    = (const float*)d_in[0];
    const float* x_l    = (const float*)d_in[2];
    const float* W_proj = (const float*)d_in[4];
    const float* b_proj = (const float*)d_in[5];
    const float* desc   = (const float*)d_in[6];
    const float* Wv     = (const float*)d_in[7];
    const float* bv     = (const float*)d_in[8];
    const float* Wu     = (const float*)d_in[9];
    const float* bu     = (const float*)d_in[10];
    const float* w_attn = (const float*)d_in[11];
    float* out = (float*)d_out;

    // workspace layout (bytes):
    //  0        : xn    bf16 [32768x512]  (33554432)
    //  33554432 : xpraw bf16 [32768x512]  (33554432)
    //  67108864 : WpT   bf16 [512x512]    (524288)
    //  67633152 : WvuT  bf16 [512x512]    (524288, fine-interleaved)
    //  68157440 : descF bf16 fragment     (32768)
    //  68190208 : bvu   f32 [512]         (2048)
    //  68192256 : invn  f32 [32768]       (131072)
    //  68323328 : slide_s f32 [2x512]     (4096)
    //  68327424 : slide_l f32 [2x512]     (4096)
    //  68331520 : Araw4 f32 [4x32768]     (524288)
    //  68855808 : part  f32 [2x32x2]      (512)
    //  68856320 : mg    f32 [2x2]         (16)
    char* w = (char*)d_ws;
    u16* xn      = (u16*)w;
    u16* xpraw   = (u16*)(w + 33554432);
    u16* WpT     = (u16*)(w + 67108864);
    u16* WvuT    = (u16*)(w + 67633152);
    u16* descF   = (u16*)(w + 68157440);
    float* bvu   = (float*)(w + 68190208);
    float* invn  = (float*)(w + 68192256);
    float* slide_s = (float*)(w + 68323328);
    float* slide_l = (float*)(w + 68327424);
    float* Araw4 = (float*)(w + 68331520);
    float* part  = (float*)(w + 68855808);
    float* mg    = (float*)(w + 68856320);

    hipMemsetAsync(slide_s, 0, 8192, stream);   // slides only
    prep_weights_kernel<<<1024, 256, 0, stream>>>(W_proj, Wv, Wu, bv, bu, desc,
                                                  WpT, WvuT, bvu, descF);

    float* cls_s = out + 10;
    float* cls_l = out + 10 + (size_t)ROWS * C_;

    for (int s = 0; s < 2; ++s) {
        const float* x = s ? x_l : x_s;
        float* cls     = s ? cls_l : cls_s;
        float* slide   = s ? slide_l : slide_s;

        rownorm_cast_kernel<<<ROWS / 4, 256, 0, stream>>>(x, xn);
        gemm_bias_kernel<<<dim3(256, 2), 256, 0, stream>>>(xn, WpT, b_proj, xpraw);
        classscore_kernel<<<256, 256, 0, stream>>>(xpraw, descF, invn, cls);
        gate_kernel<<<dim3(256, 2), 256, 0, stream>>>(xpraw, WvuT, bvu, invn, w_attn, Araw4);
        areduce_kernel<<<dim3(32, 2), 256, 0, stream>>>(Araw4, part);
        acombine_kernel<<<1, 64, 0, stream>>>(part, mg);
        pool_kernel<<<dim3(64, 2), 256, 0, stream>>>(Araw4, invn, mg, xpraw, slide);
    }
    finalize_kernel<<<1, 512, 0, stream>>>(slide_s, slide_l, desc, out);
}